// Round 15
// baseline (261.253 us; speedup 1.0000x reference)
//
#include <hip/hip_runtime.h>
#include <math.h>

#define N_NODES 100000
#define N_EDGES 1600000
#define NBINS 391        // coarse bins: dst >> 8 (391*256 = 100096 >= 100000)
#define NCHUNK 400       // edge chunks
#define CHUNK 4000       // edges per chunk (400*4000 = 1.6M exact)
#define M_H (NBINS * NCHUNK)   // 156,400 histogram entries
#define NBLK_H 611       // ceil(M_H / 256)

typedef __attribute__((ext_vector_type(8))) short bf16x8;   // MFMA A/B frag (8 bf16)
typedef __attribute__((ext_vector_type(4))) float f32x4;    // MFMA C/D frag
typedef __attribute__((ext_vector_type(2))) float f32x2;    // packed pair -> v_pk_add_f32

__device__ __forceinline__ unsigned short f2bf(float f) {   // RNE fp32->bf16
    unsigned int u = __float_as_uint(f);
    u += 0x7FFF + ((u >> 16) & 1);
    return (unsigned short)(u >> 16);
}
__device__ __forceinline__ float bf_lo(unsigned int u) { return __uint_as_float(u << 16); }
__device__ __forceinline__ float bf_hi(unsigned int u) { return __uint_as_float(u & 0xFFFF0000u); }
__device__ __forceinline__ f32x2 bfpair(unsigned int u) {
    f32x2 r; r.x = bf_lo(u); r.y = bf_hi(u); return r;
}

// ---------------- CSR build: two-level counting sort, LDS atomics only ----------------

// Pass A: per-chunk LDS histogram over coarse bins -> H[bin][chunk] (plain stores).
// NO global atomics (R1 lesson: 1.6M global atomicAdds cost 63us).
__global__ __launch_bounds__(256) void passA_kernel(const int* __restrict__ dst,
                                                    int* __restrict__ H) {
    __shared__ int lh[NBINS];
    int tid = threadIdx.x, c = blockIdx.x;
    for (int i = tid; i < NBINS; i += 256) lh[i] = 0;
    __syncthreads();
    int base = c * CHUNK;
    #pragma unroll
    for (int i = 0; i < 16; ++i) {
        int o = i * 256 + tid;
        if (o < CHUNK) atomicAdd(&lh[dst[base + o] >> 8], 1);   // LDS atomic
    }
    __syncthreads();
    for (int i = tid; i < NBINS; i += 256) H[i * NCHUNK + c] = lh[i];
}

// Pass B (parallel): scanB1 = per-block exclusive scan of H + block totals;
// scanB2 = scan of 611 totals. Top-level offset (blk2) folded into consumers.
__global__ __launch_bounds__(256) void scanB1_kernel(int* __restrict__ H,
                                                     int* __restrict__ blk2) {
    __shared__ int s[256];
    int t = threadIdx.x, i = blockIdx.x * 256 + t;
    int v = (i < M_H) ? H[i] : 0;
    s[t] = v;
    __syncthreads();
    for (int off = 1; off < 256; off <<= 1) {
        int u = (t >= off) ? s[t - off] : 0;
        __syncthreads();
        s[t] += u;
        __syncthreads();
    }
    if (i < M_H) H[i] = s[t] - v;                 // exclusive within block
    if (t == 255) blk2[blockIdx.x] = s[255];
}

__global__ __launch_bounds__(1024) void scanB2_kernel(int* __restrict__ blk2) {
    __shared__ int s[1024];
    int t = threadIdx.x;
    int v = (t < NBLK_H) ? blk2[t] : 0;
    s[t] = v;
    __syncthreads();
    for (int off = 1; off < 1024; off <<= 1) {
        int u = (t >= off) ? s[t - off] : 0;
        __syncthreads();
        s[t] += u;
        __syncthreads();
    }
    if (t < NBLK_H) blk2[t] = s[t] - v;
}

// Pass C: coarse scatter (blocks 0..399, LDS returning ranks -> rec) +
// W1T/W2T converts (blocks 400..471). x-convert AFTER passD (needs dis).
// rec[pos] = src | (dst&255)<<17  (25 bits). H base = H[idx] + blk2[idx>>8].
__global__ __launch_bounds__(256) void passC_kernel(const int* __restrict__ src,
                                                    const int* __restrict__ dst,
                                                    const int* __restrict__ H,
                                                    const int* __restrict__ blk2,
                                                    int* __restrict__ rec,
                                                    const float* __restrict__ W1,
                                                    const float* __restrict__ W2,
                                                    ushort* __restrict__ W1T,
                                                    ushort* __restrict__ W2T) {
    int b = blockIdx.x;
    if (b < NCHUNK) {
        __shared__ int base[NBINS];
        __shared__ int rk[NBINS];
        int tid = threadIdx.x;
        for (int i = tid; i < NBINS; i += 256) {
            int idx = i * NCHUNK + b;
            base[i] = H[idx] + blk2[idx >> 8];
            rk[i] = 0;
        }
        __syncthreads();
        int estart = b * CHUNK;
        #pragma unroll
        for (int i = 0; i < 16; ++i) {
            int o = i * 256 + tid;
            if (o < CHUNK) {
                int e = estart + o;
                int d = dst[e];
                int bin = d >> 8;
                int r = atomicAdd(&rk[bin], 1);          // LDS returning atomic (fast)
                rec[base[bin] + r] = src[e] | ((d & 255) << 17);
            }
        }
    } else {                                             // 72 blocks: W1T / W2T
        int j = (b - NCHUNK) * 256 + threadIdx.x;
        if (j < 16384) {
            int k = j >> 7, n = j & 127;                 // W1[k][n] -> W1T[n][k]
            W1T[n * 128 + k] = f2bf(W1[j]);
        } else {
            int q = j - 16384;                           // 2048 elements
            int k = q >> 4, n = q & 15;                  // W2[k][n] -> W2T[n][k]
            W2T[n * 128 + k] = f2bf(W2[q]);
        }
    }
}

// Pass D: per-bin fine CSR. LDS histogram over 256 nodes -> dis + absolute cnt starts,
// then LDS returning ranks place col. Degree (and thus dis) falls out for free here.
__global__ __launch_bounds__(256) void passD_kernel(const int* __restrict__ H,
                                                    const int* __restrict__ blk2,
                                                    const int* __restrict__ rec,
                                                    int* __restrict__ col,
                                                    int* __restrict__ cnt,
                                                    float* __restrict__ dis) {
    __shared__ int fh[256];
    __shared__ int s[256];
    __shared__ int run[256];
    int b = blockIdx.x, t = threadIdx.x;
    int i0 = b * NCHUNK;
    int estart = H[i0] + blk2[i0 >> 8];
    int eend;
    if (b == NBINS - 1) eend = N_EDGES;
    else { int i1 = (b + 1) * NCHUNK; eend = H[i1] + blk2[i1 >> 8]; }
    fh[t] = 0;
    __syncthreads();
    for (int e = estart + t; e < eend; e += 256)
        atomicAdd(&fh[rec[e] >> 17], 1);                 // LDS atomic
    __syncthreads();
    int v = fh[t];
    s[t] = v;
    __syncthreads();
    for (int off = 1; off < 256; off <<= 1) {
        int u = (t >= off) ? s[t - off] : 0;
        __syncthreads();
        s[t] += u;
        __syncthreads();
    }
    int node = b * 256 + t;
    int start = estart + s[t] - v;                       // absolute CSR start
    run[t] = start;
    if (node < N_NODES) {
        cnt[node] = start;
        dis[node] = rsqrtf((float)v + 1.0f);
    }
    __syncthreads();
    for (int e = estart + t; e < eend; e += 256) {
        int r = rec[e];
        int p = atomicAdd(&run[r >> 17], 1);             // LDS returning atomic
        col[p] = r & 0x1FFFF;
    }
}

// convx: x -> bf16 PRE-SCALED by dis[node] (node-major). Pure streaming, 103MB.
// 8 floats/thread (2x dwordx4 in, 1x dwordx4 out). 6250 blocks exact.
__global__ __launch_bounds__(256) void convx_kernel(const float* __restrict__ x,
                                                    const float* __restrict__ dis,
                                                    ushort* __restrict__ xb) {
    int i = blockIdx.x * 256 + threadIdx.x;              // groups of 8 floats
    float dn = dis[i >> 4];                              // node = i*8/128
    float4 v0 = *(const float4*)&x[i * 8];
    float4 v1 = *(const float4*)&x[i * 8 + 4];
    ushort4 o0, o1;
    o0.x = f2bf(v0.x * dn); o0.y = f2bf(v0.y * dn);
    o0.z = f2bf(v0.z * dn); o0.w = f2bf(v0.w * dn);
    o1.x = f2bf(v1.x * dn); o1.y = f2bf(v1.y * dn);
    o1.z = f2bf(v1.z * dn); o1.w = f2bf(v1.w * dn);
    *(ushort4*)&xb[i * 8] = o0;
    *(ushort4*)&xb[i * 8 + 4] = o1;
}

// ---------------- layer-1 aggregation (wave=node, uint2 loads: 2 edges/instr) ----------------
// R12 falsified depth-per-wave as the limiter (16-deep flat vs 8-deep). New lever:
// HALVE VMEM instruction count. 8B/lane loads -> 32 lanes cover one 256B row, so each
// 64-lane instruction fetches TWO edges' rows (half 0 = even edges, half 1 = odd).
// 16 loads/iter now cover 32 edges. Even/odd partials combine via __shfl_xor(...,32).
// col over-read <=124B past N_EDGES -> lands in dis region (in-workspace, safe).

__global__ __launch_bounds__(256) void gather1_kernel(const int* __restrict__ col,
                                                      const int* __restrict__ cnt,
                                                      const float* __restrict__ dis,
                                                      const uint2* __restrict__ xb2,
                                                      uint2* __restrict__ xa2) {
    int t = threadIdx.x;
    int node = blockIdx.x * 4 + (t >> 6);        // 25000 blocks * 4 = 100000 exact
    int lane = t & 63;
    int half = lane >> 5;                        // which edge of each pair
    int fl   = lane & 31;                        // uint2 slot in row (4 bf16)
    float dn = dis[node];
    int beg = cnt[node];
    int end = (node == N_NODES - 1) ? N_EDGES : cnt[node + 1];
    uint2 su = xb2[node * 32 + fl];              // self term (pre-scaled), half 0 only
    f32x2 a0 = bfpair(half ? 0u : su.x);
    f32x2 a1 = bfpair(half ? 0u : su.y);
    f32x2 a2 = {0.f, 0.f}, a3 = {0.f, 0.f};
    int k = beg;
    for (; k + 32 <= end; k += 32) {             // lean: 16 loads = 32 edges
        int e = k + half;
        int s0 = col[e],      s1 = col[e + 2],  s2 = col[e + 4],  s3 = col[e + 6];
        int s4 = col[e + 8],  s5 = col[e + 10], s6 = col[e + 12], s7 = col[e + 14];
        int s8 = col[e + 16], s9 = col[e + 18], sa = col[e + 20], sb = col[e + 22];
        int sc = col[e + 24], sd = col[e + 26], se = col[e + 28], sf = col[e + 30];
        uint2 u0 = xb2[s0 * 32 + fl], u1 = xb2[s1 * 32 + fl];
        uint2 u2 = xb2[s2 * 32 + fl], u3 = xb2[s3 * 32 + fl];
        uint2 u4 = xb2[s4 * 32 + fl], u5 = xb2[s5 * 32 + fl];
        uint2 u6 = xb2[s6 * 32 + fl], u7 = xb2[s7 * 32 + fl];
        uint2 u8 = xb2[s8 * 32 + fl], u9 = xb2[s9 * 32 + fl];
        uint2 ua = xb2[sa * 32 + fl], ub = xb2[sb * 32 + fl];
        uint2 uc = xb2[sc * 32 + fl], ud = xb2[sd * 32 + fl];
        uint2 ue = xb2[se * 32 + fl], uf = xb2[sf * 32 + fl];
        a0 += bfpair(u0.x); a1 += bfpair(u0.y);
        a2 += bfpair(u1.x); a3 += bfpair(u1.y);
        a0 += bfpair(u2.x); a1 += bfpair(u2.y);
        a2 += bfpair(u3.x); a3 += bfpair(u3.y);
        a0 += bfpair(u4.x); a1 += bfpair(u4.y);
        a2 += bfpair(u5.x); a3 += bfpair(u5.y);
        a0 += bfpair(u6.x); a1 += bfpair(u6.y);
        a2 += bfpair(u7.x); a3 += bfpair(u7.y);
        a0 += bfpair(u8.x); a1 += bfpair(u8.y);
        a2 += bfpair(u9.x); a3 += bfpair(u9.y);
        a0 += bfpair(ua.x); a1 += bfpair(ua.y);
        a2 += bfpair(ub.x); a3 += bfpair(ub.y);
        a0 += bfpair(uc.x); a1 += bfpair(uc.y);
        a2 += bfpair(ud.x); a3 += bfpair(ud.y);
        a0 += bfpair(ue.x); a1 += bfpair(ue.y);
        a2 += bfpair(uf.x); a3 += bfpair(uf.y);
    }
    if (k < end) {                               // single predicated 32-edge epilogue
        int e = k + half;
        int c0 = col[e],      c1 = col[e + 2],  c2 = col[e + 4],  c3 = col[e + 6];
        int c4 = col[e + 8],  c5 = col[e + 10], c6 = col[e + 12], c7 = col[e + 14];
        int c8 = col[e + 16], c9 = col[e + 18], ca = col[e + 20], cb = col[e + 22];
        int cc = col[e + 24], cd = col[e + 26], ce = col[e + 28], cf = col[e + 30];
        bool q0 = (e < end),      q1 = (e + 2 < end),  q2 = (e + 4 < end),  q3 = (e + 6 < end);
        bool q4 = (e + 8 < end),  q5 = (e + 10 < end), q6 = (e + 12 < end), q7 = (e + 14 < end);
        bool q8 = (e + 16 < end), q9 = (e + 18 < end), qa = (e + 20 < end), qb = (e + 22 < end);
        bool qc = (e + 24 < end), qd = (e + 26 < end), qe = (e + 28 < end), qf = (e + 30 < end);
        int s0 = q0 ? c0 : 0, s1 = q1 ? c1 : 0, s2 = q2 ? c2 : 0, s3 = q3 ? c3 : 0;
        int s4 = q4 ? c4 : 0, s5 = q5 ? c5 : 0, s6 = q6 ? c6 : 0, s7 = q7 ? c7 : 0;
        int s8 = q8 ? c8 : 0, s9 = q9 ? c9 : 0, sa = qa ? ca : 0, sb = qb ? cb : 0;
        int sc = qc ? cc : 0, sd = qd ? cd : 0, se = qe ? ce : 0, sf = qf ? cf : 0;
        uint2 u0 = xb2[s0 * 32 + fl], u1 = xb2[s1 * 32 + fl];
        uint2 u2 = xb2[s2 * 32 + fl], u3 = xb2[s3 * 32 + fl];
        uint2 u4 = xb2[s4 * 32 + fl], u5 = xb2[s5 * 32 + fl];
        uint2 u6 = xb2[s6 * 32 + fl], u7 = xb2[s7 * 32 + fl];
        uint2 u8 = xb2[s8 * 32 + fl], u9 = xb2[s9 * 32 + fl];
        uint2 ua = xb2[sa * 32 + fl], ub = xb2[sb * 32 + fl];
        uint2 uc = xb2[sc * 32 + fl], ud = xb2[sd * 32 + fl];
        uint2 ue = xb2[se * 32 + fl], uf = xb2[sf * 32 + fl];
        u0.x = q0 ? u0.x : 0u; u0.y = q0 ? u0.y : 0u;
        u1.x = q1 ? u1.x : 0u; u1.y = q1 ? u1.y : 0u;
        u2.x = q2 ? u2.x : 0u; u2.y = q2 ? u2.y : 0u;
        u3.x = q3 ? u3.x : 0u; u3.y = q3 ? u3.y : 0u;
        u4.x = q4 ? u4.x : 0u; u4.y = q4 ? u4.y : 0u;
        u5.x = q5 ? u5.x : 0u; u5.y = q5 ? u5.y : 0u;
        u6.x = q6 ? u6.x : 0u; u6.y = q6 ? u6.y : 0u;
        u7.x = q7 ? u7.x : 0u; u7.y = q7 ? u7.y : 0u;
        u8.x = q8 ? u8.x : 0u; u8.y = q8 ? u8.y : 0u;
        u9.x = q9 ? u9.x : 0u; u9.y = q9 ? u9.y : 0u;
        ua.x = qa ? ua.x : 0u; ua.y = qa ? ua.y : 0u;
        ub.x = qb ? ub.x : 0u; ub.y = qb ? ub.y : 0u;
        uc.x = qc ? uc.x : 0u; uc.y = qc ? uc.y : 0u;
        ud.x = qd ? ud.x : 0u; ud.y = qd ? ud.y : 0u;
        ue.x = qe ? ue.x : 0u; ue.y = qe ? ue.y : 0u;
        uf.x = qf ? uf.x : 0u; uf.y = qf ? uf.y : 0u;
        a0 += bfpair(u0.x); a1 += bfpair(u0.y);
        a2 += bfpair(u1.x); a3 += bfpair(u1.y);
        a0 += bfpair(u2.x); a1 += bfpair(u2.y);
        a2 += bfpair(u3.x); a3 += bfpair(u3.y);
        a0 += bfpair(u4.x); a1 += bfpair(u4.y);
        a2 += bfpair(u5.x); a3 += bfpair(u5.y);
        a0 += bfpair(u6.x); a1 += bfpair(u6.y);
        a2 += bfpair(u7.x); a3 += bfpair(u7.y);
        a0 += bfpair(u8.x); a1 += bfpair(u8.y);
        a2 += bfpair(u9.x); a3 += bfpair(u9.y);
        a0 += bfpair(ua.x); a1 += bfpair(ua.y);
        a2 += bfpair(ub.x); a3 += bfpair(ub.y);
        a0 += bfpair(uc.x); a1 += bfpair(uc.y);
        a2 += bfpair(ud.x); a3 += bfpair(ud.y);
        a0 += bfpair(ue.x); a1 += bfpair(ue.y);
        a2 += bfpair(uf.x); a3 += bfpair(uf.y);
    }
    a0 += a2;                                    // fold the two in-half accumulators
    a1 += a3;
    f32x2 b0, b1;                                // combine even/odd half-wave partials
    b0.x = __shfl_xor(a0.x, 32); b0.y = __shfl_xor(a0.y, 32);
    b1.x = __shfl_xor(a1.x, 32); b1.y = __shfl_xor(a1.y, 32);
    a0 += b0;
    a1 += b1;
    if (half == 0) {
        f32x2 r0 = a0 * dn, r1 = a1 * dn;
        uint2 o;
        o.x = (unsigned int)f2bf(r0.x) | ((unsigned int)f2bf(r0.y) << 16);
        o.y = (unsigned int)f2bf(r1.x) | ((unsigned int)f2bf(r1.y) << 16);
        xa2[node * 32 + fl] = o;                 // 32 lanes x 8B = 256B coalesced
    }
}

// ---------------- fused MLP: h2 = relu(xa@W1 + b1) @ W2, emitted bf16 PRE-SCALED by dis ----------------

__global__ __launch_bounds__(256) void mlp_kernel(const ushort* __restrict__ xa,
                                                  const ushort* __restrict__ W1T,
                                                  const float* __restrict__ b1,
                                                  const ushort* __restrict__ W2T,
                                                  const float* __restrict__ dis,
                                                  ushort* __restrict__ h2b) {
    __shared__ ushort sh[4][16][136];   // 136: keeps ds_read_b128 16B-aligned, banks spread
    int t = threadIdx.x;
    int wave = t >> 6, lane = t & 63;
    int l = lane & 15, quad = lane >> 4;
    int m0 = blockIdx.x * 64 + wave * 16;        // 1563*64 = 100032; waves past end idle
    bool valid = (m0 < N_NODES);                 // whole-wave predicate (no early return!)
    int row = valid ? (m0 + l) : 0;

    f32x4 acc[8] = {};
    #pragma unroll
    for (int kk = 0; kk < 4; ++kk) {
        bf16x8 a = *(const bf16x8*)&xa[row * 128 + kk * 32 + quad * 8];
        #pragma unroll
        for (int nt = 0; nt < 8; ++nt) {
            bf16x8 b = *(const bf16x8*)&W1T[(nt * 16 + l) * 128 + kk * 32 + quad * 8];
            acc[nt] = __builtin_amdgcn_mfma_f32_16x16x32_bf16(a, b, acc[nt], 0, 0, 0);
        }
    }
    #pragma unroll
    for (int nt = 0; nt < 8; ++nt) {
        float bias = b1[nt * 16 + l];
        #pragma unroll
        for (int r = 0; r < 4; ++r)
            sh[wave][quad * 4 + r][nt * 16 + l] = f2bf(fmaxf(acc[nt][r] + bias, 0.0f));
    }
    __syncthreads();   // all waves present — orders LDS writes->reads

    f32x4 acc2 = {};
    #pragma unroll
    for (int kk = 0; kk < 4; ++kk) {
        bf16x8 a2 = *(const bf16x8*)&sh[wave][l][kk * 32 + quad * 8];
        bf16x8 bw = *(const bf16x8*)&W2T[l * 128 + kk * 32 + quad * 8];
        acc2 = __builtin_amdgcn_mfma_f32_16x16x32_bf16(a2, bw, acc2, 0, 0, 0);
    }
    if (valid) {
        #pragma unroll
        for (int r = 0; r < 4; ++r) {
            int m = m0 + quad * 4 + r;
            h2b[m * 16 + l] = f2bf(acc2[r] * dis[m]);    // pre-scale by dis[row]
        }
    }
}

// ---------------- layer-2 gather + bias + log-softmax (pre-scaled bf16 h2) ----------------
// 16-deep structure (8-lane groups, 32B rows) — L2-resident, unchanged from R12.

__global__ __launch_bounds__(256) void gather2_lsm_kernel(const int* __restrict__ col,
                                                          const int* __restrict__ cnt,
                                                          const float* __restrict__ dis,
                                                          const unsigned int* __restrict__ h2p,
                                                          const float* __restrict__ b2,
                                                          float* __restrict__ out) {
    int t = threadIdx.x;
    int node = blockIdx.x * 32 + (t >> 3);       // 3125 * 32 = 100000 exact
    int c = t & 7;                               // class pair: (2c, 2c+1)
    float dn = dis[node];
    int beg = cnt[node];
    int end = (node == N_NODES - 1) ? N_EDGES : cnt[node + 1];
    unsigned int su = h2p[node * 8 + c];         // already h2*dis -> self term
    f32x2 a0 = bfpair(su);
    f32x2 a1 = {0.f, 0.f}, a2 = {0.f, 0.f}, a3 = {0.f, 0.f};
    f32x2 a4 = {0.f, 0.f}, a5 = {0.f, 0.f}, a6 = {0.f, 0.f}, a7 = {0.f, 0.f};
    int k = beg;
    for (; k + 16 <= end; k += 16) {             // lean 16-wide: no predication
        int s0 = col[k],      s1 = col[k + 1],  s2 = col[k + 2],  s3 = col[k + 3];
        int s4 = col[k + 4],  s5 = col[k + 5],  s6 = col[k + 6],  s7 = col[k + 7];
        int s8 = col[k + 8],  s9 = col[k + 9],  sa = col[k + 10], sb = col[k + 11];
        int sc = col[k + 12], sd = col[k + 13], se = col[k + 14], sf = col[k + 15];
        unsigned int u0 = h2p[s0 * 8 + c], u1 = h2p[s1 * 8 + c];
        unsigned int u2 = h2p[s2 * 8 + c], u3 = h2p[s3 * 8 + c];
        unsigned int u4 = h2p[s4 * 8 + c], u5 = h2p[s5 * 8 + c];
        unsigned int u6 = h2p[s6 * 8 + c], u7 = h2p[s7 * 8 + c];
        unsigned int u8 = h2p[s8 * 8 + c], u9 = h2p[s9 * 8 + c];
        unsigned int ua = h2p[sa * 8 + c], ub = h2p[sb * 8 + c];
        unsigned int uc = h2p[sc * 8 + c], ud = h2p[sd * 8 + c];
        unsigned int ue = h2p[se * 8 + c], uf = h2p[sf * 8 + c];
        a0 += bfpair(u0);
        a1 += bfpair(u1);
        a2 += bfpair(u2);
        a3 += bfpair(u3);
        a4 += bfpair(u4);
        a5 += bfpair(u5);
        a6 += bfpair(u6);
        a7 += bfpair(u7);
        a0 += bfpair(u8);
        a1 += bfpair(u9);
        a2 += bfpair(ua);
        a3 += bfpair(ub);
        a4 += bfpair(uc);
        a5 += bfpair(ud);
        a6 += bfpair(ue);
        a7 += bfpair(uf);
    }
    if (k < end) {                               // single predicated 16-wide epilogue
        int c0 = col[k],      c1 = col[k + 1],  c2 = col[k + 2],  c3 = col[k + 3];
        int c4 = col[k + 4],  c5 = col[k + 5],  c6 = col[k + 6],  c7 = col[k + 7];
        int c8 = col[k + 8],  c9 = col[k + 9],  ca = col[k + 10], cb = col[k + 11];
        int cc = col[k + 12], cd = col[k + 13], ce = col[k + 14], cf = col[k + 15];
        bool p1 = (k + 1 < end),  p2 = (k + 2 < end),  p3 = (k + 3 < end);
        bool p4 = (k + 4 < end),  p5 = (k + 5 < end),  p6 = (k + 6 < end),  p7 = (k + 7 < end);
        bool p8 = (k + 8 < end),  p9 = (k + 9 < end),  pa = (k + 10 < end), pb = (k + 11 < end);
        bool pc = (k + 12 < end), pd = (k + 13 < end), pe = (k + 14 < end), pf = (k + 15 < end);
        int s0 = c0;
        int s1 = p1 ? c1 : 0, s2 = p2 ? c2 : 0, s3 = p3 ? c3 : 0;
        int s4 = p4 ? c4 : 0, s5 = p5 ? c5 : 0, s6 = p6 ? c6 : 0, s7 = p7 ? c7 : 0;
        int s8 = p8 ? c8 : 0, s9 = p9 ? c9 : 0, sa = pa ? ca : 0, sb = pb ? cb : 0;
        int sc = pc ? cc : 0, sd = pd ? cd : 0, se = pe ? ce : 0, sf = pf ? cf : 0;
        unsigned int u0 = h2p[s0 * 8 + c], u1 = h2p[s1 * 8 + c];
        unsigned int u2 = h2p[s2 * 8 + c], u3 = h2p[s3 * 8 + c];
        unsigned int u4 = h2p[s4 * 8 + c], u5 = h2p[s5 * 8 + c];
        unsigned int u6 = h2p[s6 * 8 + c], u7 = h2p[s7 * 8 + c];
        unsigned int u8 = h2p[s8 * 8 + c], u9 = h2p[s9 * 8 + c];
        unsigned int ua = h2p[sa * 8 + c], ub = h2p[sb * 8 + c];
        unsigned int uc = h2p[sc * 8 + c], ud = h2p[sd * 8 + c];
        unsigned int ue = h2p[se * 8 + c], uf = h2p[sf * 8 + c];
        u1 = p1 ? u1 : 0u; u2 = p2 ? u2 : 0u; u3 = p3 ? u3 : 0u;
        u4 = p4 ? u4 : 0u; u5 = p5 ? u5 : 0u; u6 = p6 ? u6 : 0u; u7 = p7 ? u7 : 0u;
        u8 = p8 ? u8 : 0u; u9 = p9 ? u9 : 0u; ua = pa ? ua : 0u; ub = pb ? ub : 0u;
        uc = pc ? uc : 0u; ud = pd ? ud : 0u; ue = pe ? ue : 0u; uf = pf ? uf : 0u;
        a0 += bfpair(u0);
        a1 += bfpair(u1);
        a2 += bfpair(u2);
        a3 += bfpair(u3);
        a4 += bfpair(u4);
        a5 += bfpair(u5);
        a6 += bfpair(u6);
        a7 += bfpair(u7);
        a0 += bfpair(u8);
        a1 += bfpair(u9);
        a2 += bfpair(ua);
        a3 += bfpair(ub);
        a4 += bfpair(uc);
        a5 += bfpair(ud);
        a6 += bfpair(ue);
        a7 += bfpair(uf);
    }
    f32x2 r = ((a0 + a1) + (a2 + a3)) + ((a4 + a5) + (a6 + a7));
    float2 bb = ((const float2*)b2)[c];
    float v0 = r.x * dn + bb.x;
    float v1 = r.y * dn + bb.y;
    float m = fmaxf(v0, v1);
    #pragma unroll
    for (int off = 1; off < 8; off <<= 1) m = fmaxf(m, __shfl_xor(m, off, 8));
    float ssum = expf(v0 - m) + expf(v1 - m);
    #pragma unroll
    for (int off = 1; off < 8; off <<= 1) ssum += __shfl_xor(ssum, off, 8);
    float lg = m + logf(ssum);
    ((float2*)out)[node * 8 + c] = make_float2(v0 - lg, v1 - lg);
}

// ---------------- launch ----------------

extern "C" void kernel_launch(void* const* d_in, const int* in_sizes, int n_in,
                              void* d_out, int out_size, void* d_ws, size_t ws_size,
                              hipStream_t stream) {
    const float* x  = (const float*)d_in[0];
    const int*   ei = (const int*)d_in[1];
    const float* W1 = (const float*)d_in[2];
    const float* b1 = (const float*)d_in[3];
    const float* W2 = (const float*)d_in[4];
    const float* b2 = (const float*)d_in[5];
    float* out = (float*)d_out;

    const int* src = ei;              // edge_index[0]
    const int* dst = ei + N_EDGES;    // edge_index[1]

    // workspace (bytes), TOTAL = 58,440,960 (unchanged, proven safe).
    // xa's region (25.6-51.2 MB) time-shares rec (25.6-32.0) + H (32.0-32.63) during
    // CSR build; both dead before gather1 writes xa. h2b shares xb's region.
    // NOTE: gather kernels over-read col by <=124B -> lands in dis region (safe).
    char* ws = (char*)d_ws;
    ushort* xb   = (ushort*)(ws + 0);            // 25,600,000 (node-major bf16, pre-scaled)
    ushort* h2b  = (ushort*)(ws + 0);            //  3,200,000
    ushort* xa   = (ushort*)(ws + 25600000);     // 25,600,000 (node-major bf16)
    int*    rec  = (int*)   (ws + 25600000);     //  6,400,000 (coarse-binned records)
    int*    H    = (int*)   (ws + 32000000);     //    625,600 (hist / scanned bases)
    int*    col  = (int*)   (ws + 51200000);     //  6,400,000
    float*  dis  = (float*) (ws + 57600000);     //    400,000
    int*    cnt  = (int*)   (ws + 58000000);     //    400,000 (absolute CSR starts)
    int*    blk2 = (int*)   (ws + 58400000);     //      2,444 (611 scan partials)
    ushort* W1T  = (ushort*)(ws + 58404096);     //     32,768
    ushort* W2T  = (ushort*)(ws + 58436864);     //      4,096

    passA_kernel      <<<NCHUNK, 256, 0, stream>>>(dst, H);
    scanB1_kernel     <<<NBLK_H, 256, 0, stream>>>(H, blk2);
    scanB2_kernel     <<<1, 1024, 0, stream>>>(blk2);
    passC_kernel      <<<NCHUNK + 72, 256, 0, stream>>>(src, dst, H, blk2, rec,
                                                        W1, W2, W1T, W2T);
    passD_kernel      <<<NBINS, 256, 0, stream>>>(H, blk2, rec, col, cnt, dis);
    convx_kernel      <<<6250, 256, 0, stream>>>(x, dis, xb);

    gather1_kernel    <<<N_NODES / 4, 256, 0, stream>>>(col, cnt, dis,
                                                        (const uint2*)xb,
                                                        (uint2*)xa);
    mlp_kernel        <<<1563, 256, 0, stream>>>(xa, W1T, b1, W2T, dis, h2b);
    gather2_lsm_kernel<<<3125, 256, 0, stream>>>(col, cnt, dis,
                                                 (const unsigned int*)h2b, b2, out);
}

// Round 16
// 251.740 us; speedup vs baseline: 1.0378x; 1.0378x over previous
//
#include <hip/hip_runtime.h>
#include <math.h>

#define N_NODES 100000
#define N_EDGES 1600000
#define NBINS 391        // coarse bins: dst >> 8 (391*256 = 100096 >= 100000)
#define NCHUNK 400       // edge chunks
#define CHUNK 4000       // edges per chunk (400*4000 = 1.6M exact)
#define M_H (NBINS * NCHUNK)   // 156,400 histogram entries
#define NBLK_H 611       // ceil(M_H / 256)

typedef __attribute__((ext_vector_type(8))) short bf16x8;   // MFMA A/B frag (8 bf16)
typedef __attribute__((ext_vector_type(4))) float f32x4;    // MFMA C/D frag
typedef __attribute__((ext_vector_type(2))) float f32x2;    // packed pair -> v_pk_add_f32

__device__ __forceinline__ unsigned short f2bf(float f) {   // RNE fp32->bf16
    unsigned int u = __float_as_uint(f);
    u += 0x7FFF + ((u >> 16) & 1);
    return (unsigned short)(u >> 16);
}
__device__ __forceinline__ float bf_lo(unsigned int u) { return __uint_as_float(u << 16); }
__device__ __forceinline__ float bf_hi(unsigned int u) { return __uint_as_float(u & 0xFFFF0000u); }
__device__ __forceinline__ f32x2 bfpair(unsigned int u) {
    f32x2 r; r.x = bf_lo(u); r.y = bf_hi(u); return r;
}

// ---------------- CSR build: two-level counting sort, LDS atomics only ----------------

// Pass A: per-chunk LDS histogram over coarse bins -> H[bin][chunk] (plain stores).
// NO global atomics (R1 lesson: 1.6M global atomicAdds cost 63us).
__global__ __launch_bounds__(256) void passA_kernel(const int* __restrict__ dst,
                                                    int* __restrict__ H) {
    __shared__ int lh[NBINS];
    int tid = threadIdx.x, c = blockIdx.x;
    for (int i = tid; i < NBINS; i += 256) lh[i] = 0;
    __syncthreads();
    int base = c * CHUNK;
    #pragma unroll
    for (int i = 0; i < 16; ++i) {
        int o = i * 256 + tid;
        if (o < CHUNK) atomicAdd(&lh[dst[base + o] >> 8], 1);   // LDS atomic
    }
    __syncthreads();
    for (int i = tid; i < NBINS; i += 256) H[i * NCHUNK + c] = lh[i];
}

// Pass B (parallel): scanB1 = per-block exclusive scan of H + block totals;
// scanB2 = scan of 611 totals. Top-level offset (blk2) folded into consumers.
__global__ __launch_bounds__(256) void scanB1_kernel(int* __restrict__ H,
                                                     int* __restrict__ blk2) {
    __shared__ int s[256];
    int t = threadIdx.x, i = blockIdx.x * 256 + t;
    int v = (i < M_H) ? H[i] : 0;
    s[t] = v;
    __syncthreads();
    for (int off = 1; off < 256; off <<= 1) {
        int u = (t >= off) ? s[t - off] : 0;
        __syncthreads();
        s[t] += u;
        __syncthreads();
    }
    if (i < M_H) H[i] = s[t] - v;                 // exclusive within block
    if (t == 255) blk2[blockIdx.x] = s[255];
}

__global__ __launch_bounds__(1024) void scanB2_kernel(int* __restrict__ blk2) {
    __shared__ int s[1024];
    int t = threadIdx.x;
    int v = (t < NBLK_H) ? blk2[t] : 0;
    s[t] = v;
    __syncthreads();
    for (int off = 1; off < 1024; off <<= 1) {
        int u = (t >= off) ? s[t - off] : 0;
        __syncthreads();
        s[t] += u;
        __syncthreads();
    }
    if (t < NBLK_H) blk2[t] = s[t] - v;
}

// Pass C: coarse scatter (blocks 0..399, LDS returning ranks -> rec) +
// W1T/W2T converts (blocks 400..471). x-convert AFTER passD (needs dis).
// rec[pos] = src | (dst&255)<<17  (25 bits). H base = H[idx] + blk2[idx>>8].
__global__ __launch_bounds__(256) void passC_kernel(const int* __restrict__ src,
                                                    const int* __restrict__ dst,
                                                    const int* __restrict__ H,
                                                    const int* __restrict__ blk2,
                                                    int* __restrict__ rec,
                                                    const float* __restrict__ W1,
                                                    const float* __restrict__ W2,
                                                    ushort* __restrict__ W1T,
                                                    ushort* __restrict__ W2T) {
    int b = blockIdx.x;
    if (b < NCHUNK) {
        __shared__ int base[NBINS];
        __shared__ int rk[NBINS];
        int tid = threadIdx.x;
        for (int i = tid; i < NBINS; i += 256) {
            int idx = i * NCHUNK + b;
            base[i] = H[idx] + blk2[idx >> 8];
            rk[i] = 0;
        }
        __syncthreads();
        int estart = b * CHUNK;
        #pragma unroll
        for (int i = 0; i < 16; ++i) {
            int o = i * 256 + tid;
            if (o < CHUNK) {
                int e = estart + o;
                int d = dst[e];
                int bin = d >> 8;
                int r = atomicAdd(&rk[bin], 1);          // LDS returning atomic (fast)
                rec[base[bin] + r] = src[e] | ((d & 255) << 17);
            }
        }
    } else {                                             // 72 blocks: W1T / W2T
        int j = (b - NCHUNK) * 256 + threadIdx.x;
        if (j < 16384) {
            int k = j >> 7, n = j & 127;                 // W1[k][n] -> W1T[n][k]
            W1T[n * 128 + k] = f2bf(W1[j]);
        } else {
            int q = j - 16384;                           // 2048 elements
            int k = q >> 4, n = q & 15;                  // W2[k][n] -> W2T[n][k]
            W2T[n * 128 + k] = f2bf(W2[q]);
        }
    }
}

// Pass D: per-bin fine CSR. LDS histogram over 256 nodes -> dis + absolute cnt starts,
// then LDS returning ranks place col. Degree (and thus dis) falls out for free here.
__global__ __launch_bounds__(256) void passD_kernel(const int* __restrict__ H,
                                                    const int* __restrict__ blk2,
                                                    const int* __restrict__ rec,
                                                    int* __restrict__ col,
                                                    int* __restrict__ cnt,
                                                    float* __restrict__ dis) {
    __shared__ int fh[256];
    __shared__ int s[256];
    __shared__ int run[256];
    int b = blockIdx.x, t = threadIdx.x;
    int i0 = b * NCHUNK;
    int estart = H[i0] + blk2[i0 >> 8];
    int eend;
    if (b == NBINS - 1) eend = N_EDGES;
    else { int i1 = (b + 1) * NCHUNK; eend = H[i1] + blk2[i1 >> 8]; }
    fh[t] = 0;
    __syncthreads();
    for (int e = estart + t; e < eend; e += 256)
        atomicAdd(&fh[rec[e] >> 17], 1);                 // LDS atomic
    __syncthreads();
    int v = fh[t];
    s[t] = v;
    __syncthreads();
    for (int off = 1; off < 256; off <<= 1) {
        int u = (t >= off) ? s[t - off] : 0;
        __syncthreads();
        s[t] += u;
        __syncthreads();
    }
    int node = b * 256 + t;
    int start = estart + s[t] - v;                       // absolute CSR start
    run[t] = start;
    if (node < N_NODES) {
        cnt[node] = start;
        dis[node] = rsqrtf((float)v + 1.0f);
    }
    __syncthreads();
    for (int e = estart + t; e < eend; e += 256) {
        int r = rec[e];
        int p = atomicAdd(&run[r >> 17], 1);             // LDS returning atomic
        col[p] = r & 0x1FFFF;
    }
}

// convx: x -> bf16 PRE-SCALED by dis[node] (node-major). Pure streaming, 77MB.
__global__ __launch_bounds__(256) void convx_kernel(const float* __restrict__ x,
                                                    const float* __restrict__ dis,
                                                    ushort* __restrict__ xb) {
    int i = blockIdx.x * 256 + threadIdx.x;              // groups of 4 floats
    float dn = dis[i >> 5];                              // node = i*4/128
    float4 v = *(const float4*)&x[i * 4];
    ushort4 o;
    o.x = f2bf(v.x * dn); o.y = f2bf(v.y * dn);
    o.z = f2bf(v.z * dn); o.w = f2bf(v.w * dn);
    *(ushort4*)&xb[i * 4] = o;
}

// ---------------- layer-1 aggregation (wave=node, 64 lanes=128 feats) ----------------
// MEASURED-BEST variant (R7: gather1 60.6us): lean unpredicated 8-wide main loop +
// ONE predicated 8-wide epilogue. Five structural variants bracketed 60.6-77.7us with
// FETCH_SIZE pinned at 190MB -> L3->L2 random 256B-row service-rate wall (~3.1 TB/s).
// col over-read <=28B past N_EDGES -> lands in dis region (in-workspace, safe).

__global__ __launch_bounds__(256) void gather1_kernel(const int* __restrict__ col,
                                                      const int* __restrict__ cnt,
                                                      const float* __restrict__ dis,
                                                      const unsigned int* __restrict__ xb,
                                                      unsigned int* __restrict__ xa) {
    int t = threadIdx.x;
    int node = blockIdx.x * 4 + (t >> 6);        // 25000 blocks * 4 = 100000 exact
    int lane = t & 63;
    float dn = dis[node];
    int beg = cnt[node];
    int end = (node == N_NODES - 1) ? N_EDGES : cnt[node + 1];
    unsigned int su = xb[node * 64 + lane];      // already x*dis -> self term
    f32x2 a0 = bfpair(su);
    f32x2 a1 = {0.f, 0.f}, a2 = {0.f, 0.f}, a3 = {0.f, 0.f};
    f32x2 a4 = {0.f, 0.f}, a5 = {0.f, 0.f}, a6 = {0.f, 0.f}, a7 = {0.f, 0.f};
    int k = beg;
    for (; k + 8 <= end; k += 8) {               // lean: no predication
        int s0 = col[k], s1 = col[k + 1], s2 = col[k + 2], s3 = col[k + 3];
        int s4 = col[k + 4], s5 = col[k + 5], s6 = col[k + 6], s7 = col[k + 7];
        unsigned int u0 = xb[s0 * 64 + lane], u1 = xb[s1 * 64 + lane];
        unsigned int u2 = xb[s2 * 64 + lane], u3 = xb[s3 * 64 + lane];
        unsigned int u4 = xb[s4 * 64 + lane], u5 = xb[s5 * 64 + lane];
        unsigned int u6 = xb[s6 * 64 + lane], u7 = xb[s7 * 64 + lane];
        a0 += bfpair(u0);
        a1 += bfpair(u1);
        a2 += bfpair(u2);
        a3 += bfpair(u3);
        a4 += bfpair(u4);
        a5 += bfpair(u5);
        a6 += bfpair(u6);
        a7 += bfpair(u7);
    }
    if (k < end) {                               // single predicated 8-wide epilogue
        int c0 = col[k],     c1 = col[k + 1], c2 = col[k + 2], c3 = col[k + 3];
        int c4 = col[k + 4], c5 = col[k + 5], c6 = col[k + 6], c7 = col[k + 7];
        bool p1 = (k + 1 < end), p2 = (k + 2 < end), p3 = (k + 3 < end);
        bool p4 = (k + 4 < end), p5 = (k + 5 < end), p6 = (k + 6 < end), p7 = (k + 7 < end);
        int s0 = c0;
        int s1 = p1 ? c1 : 0, s2 = p2 ? c2 : 0, s3 = p3 ? c3 : 0;
        int s4 = p4 ? c4 : 0, s5 = p5 ? c5 : 0, s6 = p6 ? c6 : 0, s7 = p7 ? c7 : 0;
        unsigned int u0 = xb[s0 * 64 + lane], u1 = xb[s1 * 64 + lane];
        unsigned int u2 = xb[s2 * 64 + lane], u3 = xb[s3 * 64 + lane];
        unsigned int u4 = xb[s4 * 64 + lane], u5 = xb[s5 * 64 + lane];
        unsigned int u6 = xb[s6 * 64 + lane], u7 = xb[s7 * 64 + lane];
        u1 = p1 ? u1 : 0u; u2 = p2 ? u2 : 0u; u3 = p3 ? u3 : 0u;
        u4 = p4 ? u4 : 0u; u5 = p5 ? u5 : 0u; u6 = p6 ? u6 : 0u; u7 = p7 ? u7 : 0u;
        a0 += bfpair(u0);
        a1 += bfpair(u1);
        a2 += bfpair(u2);
        a3 += bfpair(u3);
        a4 += bfpair(u4);
        a5 += bfpair(u5);
        a6 += bfpair(u6);
        a7 += bfpair(u7);
    }
    f32x2 r = (((a0 + a1) + (a2 + a3)) + ((a4 + a5) + (a6 + a7))) * dn;
    xa[node * 64 + lane] = (unsigned int)f2bf(r.x) | ((unsigned int)f2bf(r.y) << 16);
}

// ---------------- fused MLP: h2 = relu(xa@W1 + b1) @ W2, emitted bf16 PRE-SCALED by dis ----------------

__global__ __launch_bounds__(256) void mlp_kernel(const ushort* __restrict__ xa,
                                                  const ushort* __restrict__ W1T,
                                                  const float* __restrict__ b1,
                                                  const ushort* __restrict__ W2T,
                                                  const float* __restrict__ dis,
                                                  ushort* __restrict__ h2b) {
    __shared__ ushort sh[4][16][136];   // 136: keeps ds_read_b128 16B-aligned, banks spread
    int t = threadIdx.x;
    int wave = t >> 6, lane = t & 63;
    int l = lane & 15, quad = lane >> 4;
    int m0 = blockIdx.x * 64 + wave * 16;        // 1563*64 = 100032; waves past end idle
    bool valid = (m0 < N_NODES);                 // whole-wave predicate (no early return!)
    int row = valid ? (m0 + l) : 0;

    f32x4 acc[8] = {};
    #pragma unroll
    for (int kk = 0; kk < 4; ++kk) {
        bf16x8 a = *(const bf16x8*)&xa[row * 128 + kk * 32 + quad * 8];
        #pragma unroll
        for (int nt = 0; nt < 8; ++nt) {
            bf16x8 b = *(const bf16x8*)&W1T[(nt * 16 + l) * 128 + kk * 32 + quad * 8];
            acc[nt] = __builtin_amdgcn_mfma_f32_16x16x32_bf16(a, b, acc[nt], 0, 0, 0);
        }
    }
    #pragma unroll
    for (int nt = 0; nt < 8; ++nt) {
        float bias = b1[nt * 16 + l];
        #pragma unroll
        for (int r = 0; r < 4; ++r)
            sh[wave][quad * 4 + r][nt * 16 + l] = f2bf(fmaxf(acc[nt][r] + bias, 0.0f));
    }
    __syncthreads();   // all waves present — orders LDS writes->reads

    f32x4 acc2 = {};
    #pragma unroll
    for (int kk = 0; kk < 4; ++kk) {
        bf16x8 a2 = *(const bf16x8*)&sh[wave][l][kk * 32 + quad * 8];
        bf16x8 bw = *(const bf16x8*)&W2T[l * 128 + kk * 32 + quad * 8];
        acc2 = __builtin_amdgcn_mfma_f32_16x16x32_bf16(a2, bw, acc2, 0, 0, 0);
    }
    if (valid) {
        #pragma unroll
        for (int r = 0; r < 4; ++r) {
            int m = m0 + quad * 4 + r;
            h2b[m * 16 + l] = f2bf(acc2[r] * dis[m]);    // pre-scale by dis[row]
        }
    }
}

// ---------------- layer-2 gather + bias + log-softmax (pre-scaled bf16 h2) ----------------
// Same structure: lean 8-wide main + single predicated epilogue.

__global__ __launch_bounds__(256) void gather2_lsm_kernel(const int* __restrict__ col,
                                                          const int* __restrict__ cnt,
                                                          const float* __restrict__ dis,
                                                          const unsigned int* __restrict__ h2p,
                                                          const float* __restrict__ b2,
                                                          float* __restrict__ out) {
    int t = threadIdx.x;
    int node = blockIdx.x * 32 + (t >> 3);       // 3125 * 32 = 100000 exact
    int c = t & 7;                               // class pair: (2c, 2c+1)
    float dn = dis[node];
    int beg = cnt[node];
    int end = (node == N_NODES - 1) ? N_EDGES : cnt[node + 1];
    unsigned int su = h2p[node * 8 + c];         // already h2*dis -> self term
    f32x2 a0 = bfpair(su);
    f32x2 a1 = {0.f, 0.f}, a2 = {0.f, 0.f}, a3 = {0.f, 0.f};
    f32x2 a4 = {0.f, 0.f}, a5 = {0.f, 0.f}, a6 = {0.f, 0.f}, a7 = {0.f, 0.f};
    int k = beg;
    for (; k + 8 <= end; k += 8) {               // lean: no predication
        int s0 = col[k], s1 = col[k + 1], s2 = col[k + 2], s3 = col[k + 3];
        int s4 = col[k + 4], s5 = col[k + 5], s6 = col[k + 6], s7 = col[k + 7];
        unsigned int u0 = h2p[s0 * 8 + c], u1 = h2p[s1 * 8 + c];
        unsigned int u2 = h2p[s2 * 8 + c], u3 = h2p[s3 * 8 + c];
        unsigned int u4 = h2p[s4 * 8 + c], u5 = h2p[s5 * 8 + c];
        unsigned int u6 = h2p[s6 * 8 + c], u7 = h2p[s7 * 8 + c];
        a0 += bfpair(u0);
        a1 += bfpair(u1);
        a2 += bfpair(u2);
        a3 += bfpair(u3);
        a4 += bfpair(u4);
        a5 += bfpair(u5);
        a6 += bfpair(u6);
        a7 += bfpair(u7);
    }
    if (k < end) {                               // single predicated 8-wide epilogue
        int c0 = col[k],     c1 = col[k + 1], c2 = col[k + 2], c3 = col[k + 3];
        int c4 = col[k + 4], c5 = col[k + 5], c6 = col[k + 6], c7 = col[k + 7];
        bool p1 = (k + 1 < end), p2 = (k + 2 < end), p3 = (k + 3 < end);
        bool p4 = (k + 4 < end), p5 = (k + 5 < end), p6 = (k + 6 < end), p7 = (k + 7 < end);
        int s0 = c0;
        int s1 = p1 ? c1 : 0, s2 = p2 ? c2 : 0, s3 = p3 ? c3 : 0;
        int s4 = p4 ? c4 : 0, s5 = p5 ? c5 : 0, s6 = p6 ? c6 : 0, s7 = p7 ? c7 : 0;
        unsigned int u0 = h2p[s0 * 8 + c], u1 = h2p[s1 * 8 + c];
        unsigned int u2 = h2p[s2 * 8 + c], u3 = h2p[s3 * 8 + c];
        unsigned int u4 = h2p[s4 * 8 + c], u5 = h2p[s5 * 8 + c];
        unsigned int u6 = h2p[s6 * 8 + c], u7 = h2p[s7 * 8 + c];
        u1 = p1 ? u1 : 0u; u2 = p2 ? u2 : 0u; u3 = p3 ? u3 : 0u;
        u4 = p4 ? u4 : 0u; u5 = p5 ? u5 : 0u; u6 = p6 ? u6 : 0u; u7 = p7 ? u7 : 0u;
        a0 += bfpair(u0);
        a1 += bfpair(u1);
        a2 += bfpair(u2);
        a3 += bfpair(u3);
        a4 += bfpair(u4);
        a5 += bfpair(u5);
        a6 += bfpair(u6);
        a7 += bfpair(u7);
    }
    f32x2 r = ((a0 + a1) + (a2 + a3)) + ((a4 + a5) + (a6 + a7));
    float2 bb = ((const float2*)b2)[c];
    float v0 = r.x * dn + bb.x;
    float v1 = r.y * dn + bb.y;
    float m = fmaxf(v0, v1);
    #pragma unroll
    for (int off = 1; off < 8; off <<= 1) m = fmaxf(m, __shfl_xor(m, off, 8));
    float ssum = expf(v0 - m) + expf(v1 - m);
    #pragma unroll
    for (int off = 1; off < 8; off <<= 1) ssum += __shfl_xor(ssum, off, 8);
    float lg = m + logf(ssum);
    ((float2*)out)[node * 8 + c] = make_float2(v0 - lg, v1 - lg);
}

// ---------------- launch ----------------

extern "C" void kernel_launch(void* const* d_in, const int* in_sizes, int n_in,
                              void* d_out, int out_size, void* d_ws, size_t ws_size,
                              hipStream_t stream) {
    const float* x  = (const float*)d_in[0];
    const int*   ei = (const int*)d_in[1];
    const float* W1 = (const float*)d_in[2];
    const float* b1 = (const float*)d_in[3];
    const float* W2 = (const float*)d_in[4];
    const float* b2 = (const float*)d_in[5];
    float* out = (float*)d_out;

    const int* src = ei;              // edge_index[0]
    const int* dst = ei + N_EDGES;    // edge_index[1]

    // workspace (bytes), TOTAL = 58,440,960 (unchanged, proven safe).
    // xa's region (25.6-51.2 MB) time-shares rec (25.6-32.0) + H (32.0-32.63) during
    // CSR build; both dead before gather1 writes xa. h2b shares xb's region.
    // NOTE: gather kernels over-read col by <=28B -> lands in dis region (safe).
    char* ws = (char*)d_ws;
    ushort* xb   = (ushort*)(ws + 0);            // 25,600,000 (node-major bf16, pre-scaled)
    ushort* h2b  = (ushort*)(ws + 0);            //  3,200,000
    ushort* xa   = (ushort*)(ws + 25600000);     // 25,600,000 (node-major bf16)
    int*    rec  = (int*)   (ws + 25600000);     //  6,400,000 (coarse-binned records)
    int*    H    = (int*)   (ws + 32000000);     //    625,600 (hist / scanned bases)
    int*    col  = (int*)   (ws + 51200000);     //  6,400,000
    float*  dis  = (float*) (ws + 57600000);     //    400,000
    int*    cnt  = (int*)   (ws + 58000000);     //    400,000 (absolute CSR starts)
    int*    blk2 = (int*)   (ws + 58400000);     //      2,444 (611 scan partials)
    ushort* W1T  = (ushort*)(ws + 58404096);     //     32,768
    ushort* W2T  = (ushort*)(ws + 58436864);     //      4,096

    passA_kernel      <<<NCHUNK, 256, 0, stream>>>(dst, H);
    scanB1_kernel     <<<NBLK_H, 256, 0, stream>>>(H, blk2);
    scanB2_kernel     <<<1, 1024, 0, stream>>>(blk2);
    passC_kernel      <<<NCHUNK + 72, 256, 0, stream>>>(src, dst, H, blk2, rec,
                                                        W1, W2, W1T, W2T);
    passD_kernel      <<<NBINS, 256, 0, stream>>>(H, blk2, rec, col, cnt, dis);
    convx_kernel      <<<12500, 256, 0, stream>>>(x, dis, xb);

    gather1_kernel    <<<N_NODES / 4, 256, 0, stream>>>(col, cnt, dis,
                                                        (const unsigned int*)xb,
                                                        (unsigned int*)xa);
    mlp_kernel        <<<1563, 256, 0, stream>>>(xa, W1T, b1, W2T, dis, h2b);
    gather2_lsm_kernel<<<3125, 256, 0, stream>>>(col, cnt, dis,
                                                 (const unsigned int*)h2b, b2, out);
}